// Round 20
// baseline (317.777 us; speedup 1.0000x reference)
//
#include <hip/hip_runtime.h>
#include <math.h>

// B=2048 windows, N=64 tokens, C=192 channels, 6 heads x 32 dim, 3C=576
#define SCALE_Q 0.17677669529663687f

typedef _Float16 f16;
typedef _Float16 f16x4 __attribute__((ext_vector_type(4)));
typedef _Float16 f16x8 __attribute__((ext_vector_type(8)));
typedef float float4v __attribute__((ext_vector_type(4)));

// Precomputed relative-position bias tile [6][64][64] (f16), L2-hot at use.
__device__ f16 g_biasg[6 * 64 * 64];

// Bijective XCD-chunk swizzle: window = ((x&7)<<8)|(x>>3). Consecutive-ID
// blocks round-robin onto the 8 XCDs; under this map XCD k owns the
// contiguous window chunk [k*256, (k+1)*256) in EVERY kernel -> producer/
// consumer pairs (qkv->attn T, fft->attn XI, attn->proj O) stay on one L2
// AND attn's +/-1-window halo is chunk-local. (r10 swizzled only attn and
// lost producer affinity -> regression; this applies it everywhere.)
__device__ __forceinline__ int swz_win(int x) { return ((x & 7) << 8) | (x >> 3); }

// cos(k*pi/4), k in [0,8) — branchless
__device__ __forceinline__ float cos8(int k) {
    float m = (k & 1) ? 0.70710678118654752f : ((k & 2) ? 0.f : 1.f);
    return (k >= 3 && k <= 5) ? -m : m;
}

// Fast GELU: A&S 7.1.26 erf approx, |err| <= 1.5e-7.
__device__ __forceinline__ float gelu_f(float v) {
    float az = fabsf(v) * 0.70710678118654752f;
    float t = 1.0f / fmaf(az, 0.3275911f, 1.0f);
    float p = t * fmaf(t, fmaf(t, fmaf(t, fmaf(t, 1.061405429f, -1.453152027f),
                                       1.421413741f), -0.284496736f), 0.254829592f);
    float erfv = 1.0f - p * __expf(-az * az);
    erfv = copysignf(erfv, v);
    return 0.5f * v * (1.0f + erfv);
}

// ---------------------------------------------------------------------------
// Prep: all weights to f16 MFMA-fragment order (512 elems/fragment):
//   Wf[(o16*6+kc)*512 + lane*8 + j] = W[o16*16+(lane&15)][kc*32+(lane>>4)*8+j]
// qkvf (576x192) | projf (192x192) | q1f | q2f (192x192) + bias tile.
// ---------------------------------------------------------------------------
__global__ __launch_bounds__(256) void k_prep(
    const float* __restrict__ qkvw, const float* __restrict__ q1w,
    const float* __restrict__ q2w, const float* __restrict__ projw,
    const float* __restrict__ rpb, const int* __restrict__ relidx,
    f16* __restrict__ qkvf, f16* __restrict__ projf,
    f16* __restrict__ q1f, f16* __restrict__ q2f)
{
    int idx = blockIdx.x * 256 + threadIdx.x;
    if (idx < 221184) {
        int i = idx;
        const float* src;
        f16* dst;
        if (i < 110592)      { src = qkvw;  dst = qkvf; }
        else if (i < 147456) { i -= 110592; src = projw; dst = projf; }
        else if (i < 184320) { i -= 147456; src = q1w;   dst = q1f; }
        else                 { i -= 184320; src = q2w;   dst = q2f; }
        int frag = i >> 9, rem = i & 511;
        int lane = rem >> 3, j = rem & 7;
        int o16 = frag / 6, kc = frag - o16 * 6;
        int row = o16 * 16 + (lane & 15);
        int col = kc * 32 + (lane >> 4) * 8 + j;
        dst[i] = (f16)src[row * 192 + col];
    } else if (idx < 245760) {
        int i = idx - 221184;
        int h = i >> 12, nm = i & 4095;
        g_biasg[h * 4096 + nm] = (f16)rpb[relidx[nm] * 6 + h];
    }
}

// ---------------------------------------------------------------------------
// Fully fused FFT branch, one block (512 thr, 8 waves) per window (swizzled).
// Stages x f32: coalesced loads -> Y (row-major, stride 198) -> vectorized
// transpose pass -> XT channel-major. ph1/ph4: rw=w&3, ch=w>>2; DFT matrix
// per-lane (cos8). ph2/ph3: h2=w&1, q4=w>>1; weights fragment-order (L2-hot).
// ---------------------------------------------------------------------------
__global__ __launch_bounds__(512, 4) void k_fft(
    const float* __restrict__ x, const f16* __restrict__ q1f,
    const f16* __restrict__ q2f, f16* __restrict__ xifft)
{
    __shared__ f16 XT[192 * 72];
    __shared__ f16 Y[64 * 200];
    const int b = swz_win(blockIdx.x), tid = threadIdx.x;
    const long gbase = (long)b * 12288;
    const int w = tid >> 6, l = tid & 63, lo = l & 15, hi = l >> 4;
    const int rw = w & 3, ch = w >> 2;
    const int h2 = w & 1, q4 = w >> 1;

    // stage a: x f32 coalesced -> Y row-major f16 (stride 198)
    #pragma unroll
    for (int it = 0; it < 6; ++it) {
        int idx = tid + it * 512;            // 3072 float4s
        int r = idx / 48, c4 = idx % 48;
        float4v v = *(const float4v*)&x[gbase + r * 192 + c4 * 4];
        f16x4 hv = {(f16)v.x, (f16)v.y, (f16)v.z, (f16)v.w};
        *(f16x4*)&Y[r * 198 + c4 * 4] = hv;
    }
    __syncthreads();
    // stage b: transpose Y -> XT[c][hw], vector writes
    #pragma unroll
    for (int it = 0; it < 3; ++it) {
        int idx = tid + it * 512;            // 1536 f16x8 tasks
        int c = idx >> 3, g8 = idx & 7;
        f16x8 o;
        #pragma unroll
        for (int j = 0; j < 8; ++j) o[j] = Y[(g8 * 8 + j) * 198 + c];
        *(f16x8*)&XT[c * 72 + g8 * 8] = o;
    }
    __syncthreads();

    // ph1: y1[uv][c] = sum_hw L[uv][hw] x^T[c][hw]
    {
        f16x8 afr[2];
        int u = (rw * 16 + lo) >> 3, v = (rw * 16 + lo) & 7;
        #pragma unroll
        for (int kc = 0; kc < 2; ++kc) {
            int cg = kc * 4 + hi;
            #pragma unroll
            for (int e = 0; e < 8; ++e)
                afr[kc][e] = (f16)cos8((u * cg + v * e) & 7);
        }
        float4v acc[6];
        #pragma unroll
        for (int nt = 0; nt < 6; ++nt) acc[nt] = (float4v){0.f,0.f,0.f,0.f};
        #pragma unroll
        for (int kc = 0; kc < 2; ++kc)
            #pragma unroll
            for (int nt = 0; nt < 6; ++nt) {
                f16x8 bf = *(const f16x8*)&XT[(ch * 96 + nt * 16 + lo) * 72 + kc * 32 + hi * 8];
                acc[nt] = __builtin_amdgcn_mfma_f32_16x16x32_f16(afr[kc], bf, acc[nt], 0, 0, 0);
            }
        __syncthreads();   // staging reads of Y done before y1 overwrite
        #pragma unroll
        for (int nt = 0; nt < 6; ++nt)
            #pragma unroll
            for (int r = 0; r < 4; ++r)
                Y[(rw * 16 + hi * 4 + r) * 200 + ch * 96 + nt * 16 + lo] = (f16)acc[nt][r];
    }
    __syncthreads();   // y1 visible; XT(x^T) reads done

    // ph2: y2[uv][o] = gelu(sum_c y1[uv][c] q1[o][c]) -> XT region, stride 216
    {
        float4v acc[2][3];
        #pragma unroll
        for (int mt = 0; mt < 2; ++mt)
            #pragma unroll
            for (int nj = 0; nj < 3; ++nj) acc[mt][nj] = (float4v){0.f,0.f,0.f,0.f};
        for (int kc = 0; kc < 6; ++kc) {
            f16x8 a[2];
            #pragma unroll
            for (int mt = 0; mt < 2; ++mt)
                a[mt] = *(const f16x8*)&Y[(h2 * 32 + mt * 16 + lo) * 200 + kc * 32 + hi * 8];
            #pragma unroll
            for (int nj = 0; nj < 3; ++nj) {
                f16x8 bf = *(const f16x8*)&q1f[((q4 * 3 + nj) * 6 + kc) * 512 + l * 8];
                #pragma unroll
                for (int mt = 0; mt < 2; ++mt)
                    acc[mt][nj] = __builtin_amdgcn_mfma_f32_16x16x32_f16(a[mt], bf, acc[mt][nj], 0, 0, 0);
            }
        }
        f16* y2 = XT;
        #pragma unroll
        for (int mt = 0; mt < 2; ++mt)
            #pragma unroll
            for (int nj = 0; nj < 3; ++nj)
                #pragma unroll
                for (int r = 0; r < 4; ++r)
                    y2[(h2 * 32 + mt * 16 + hi * 4 + r) * 216 + (q4 * 3 + nj) * 16 + lo] =
                        (f16)gelu_f(acc[mt][nj][r]);
    }
    __syncthreads();   // y2 visible; Y(y1) reads done

    // ph3: y3T[o][uv] = sum_c q2[o][c] y2[uv][c] -> Y region, swizzled cols
    {
        const f16* y2 = XT;
        float4v acc[3][2];
        #pragma unroll
        for (int jo = 0; jo < 3; ++jo)
            #pragma unroll
            for (int ju = 0; ju < 2; ++ju) acc[jo][ju] = (float4v){0.f,0.f,0.f,0.f};
        for (int kc = 0; kc < 6; ++kc) {
            f16x8 bf2[2];
            #pragma unroll
            for (int ju = 0; ju < 2; ++ju)
                bf2[ju] = *(const f16x8*)&y2[((h2 * 2 + ju) * 16 + lo) * 216 + kc * 32 + hi * 8];
            #pragma unroll
            for (int jo = 0; jo < 3; ++jo) {
                f16x8 a = *(const f16x8*)&q2f[((q4 * 3 + jo) * 6 + kc) * 512 + l * 8];
                #pragma unroll
                for (int ju = 0; ju < 2; ++ju)
                    acc[jo][ju] = __builtin_amdgcn_mfma_f32_16x16x32_f16(a, bf2[ju], acc[jo][ju], 0, 0, 0);
            }
        }
        __syncthreads();   // y2 reads done before overwriting Y
        #pragma unroll
        for (int jo = 0; jo < 3; ++jo)
            #pragma unroll
            for (int ju = 0; ju < 2; ++ju)
                #pragma unroll
                for (int r = 0; r < 4; ++r) {
                    int row = (q4 * 3 + jo) * 16 + hi * 4 + r;
                    int col = (h2 * 2 + ju) * 16 + lo;
                    Y[row * 64 + (col ^ ((row & 7) << 3))] = (f16)acc[jo][ju][r];
                }
    }
    __syncthreads();   // y3T visible

    // ph4: xifft[o][hw] = (1/64) sum_uv y3T[o][uv] L[hw][uv]
    {
        f16x8 bfr[2][2];
        #pragma unroll
        for (int t = 0; t < 2; ++t) {
            int hw = (ch * 2 + t) * 16 + lo;
            int hu = hw >> 3, hv = hw & 7;
            #pragma unroll
            for (int kc = 0; kc < 2; ++kc) {
                int cg = kc * 4 + hi;
                #pragma unroll
                for (int e = 0; e < 8; ++e)
                    bfr[t][kc][e] = (f16)cos8((hu * cg + hv * e) & 7);
            }
        }
        float4v acc[6];
        #pragma unroll
        for (int jt = 0; jt < 6; ++jt) acc[jt] = (float4v){0.f,0.f,0.f,0.f};
        #pragma unroll
        for (int kc = 0; kc < 2; ++kc)
            #pragma unroll
            for (int j = 0; j < 3; ++j) {
                int row = (rw * 3 + j) * 16 + lo;
                f16x8 a = *(const f16x8*)&Y[row * 64 + ((kc * 32 + hi * 8) ^ ((row & 7) << 3))];
                #pragma unroll
                for (int t = 0; t < 2; ++t)
                    acc[j * 2 + t] = __builtin_amdgcn_mfma_f32_16x16x32_f16(a, bfr[t][kc], acc[j * 2 + t], 0, 0, 0);
            }
        #pragma unroll
        for (int j = 0; j < 3; ++j)
            #pragma unroll
            for (int t = 0; t < 2; ++t)
                #pragma unroll
                for (int r = 0; r < 4; ++r)
                    xifft[gbase + ((rw * 3 + j) * 16 + hi * 4 + r) * 64 + (ch * 2 + t) * 16 + lo] =
                        (f16)(acc[j * 2 + t][r] * 0.015625f);
    }
}

// ---------------------------------------------------------------------------
// fp16 MFMA GEMM, K=192, weights in fragment order (no Ws staging, no loop
// barriers). Window-swizzled row tile (row0 = swz(blockIdx.x)*64).
// GROUPED=true : A f32 (x), out grouped [(o/32)][row][o%32] f16 (qkv).
// GROUPED=false: A f16, out row-major [M][192] f32 (proj).
// ---------------------------------------------------------------------------
template<int NT, bool GROUPED>
__global__ __launch_bounds__(256) void gemm_frag(
    const void* __restrict__ Ain, const f16* __restrict__ Wf,
    const float* __restrict__ bias, void* __restrict__ out)
{
    __shared__ f16 As[64 * 200];
    __shared__ char bnc_raw[GROUPED ? 64 * 72 * 2 : 64 * 68 * 4];
    const int tid = threadIdx.x;
    const long row0 = (long)swz_win(blockIdx.x) * 64;
    const int w = tid >> 6, l = tid & 63, lo = l & 15, hi = l >> 4;

    if (GROUPED) {
        const float* A = (const float*)Ain;
        for (int idx = tid; idx < 3072; idx += 256) {
            int r = idx / 48, c4 = idx % 48;
            float4v v = *(const float4v*)&A[(row0 + r) * 192 + c4 * 4];
            f16x4 hv = {(f16)v.x, (f16)v.y, (f16)v.z, (f16)v.w};
            *(f16x4*)&As[r * 200 + c4 * 4] = hv;
        }
    } else {
        const f16* A = (const f16*)Ain;
        for (int idx = tid; idx < 1536; idx += 256) {
            int r = idx / 24, c8 = idx % 24;
            *(f16x8*)&As[r * 200 + c8 * 8] =
                *(const f16x8*)&A[(row0 + r) * 192 + c8 * 8];
        }
    }
    __syncthreads();

    for (int ot = 0; ot < NT; ++ot) {
        float4v acc[4];
        #pragma unroll
        for (int nt = 0; nt < 4; ++nt) acc[nt] = (float4v){0.f,0.f,0.f,0.f};
        #pragma unroll
        for (int kc = 0; kc < 6; ++kc) {
            f16x8 a = *(const f16x8*)&As[(w * 16 + lo) * 200 + kc * 32 + hi * 8];
            #pragma unroll
            for (int nt = 0; nt < 4; ++nt) {
                f16x8 bf = *(const f16x8*)&Wf[(long)(((ot * 4 + nt) * 6 + kc)) * 512 + l * 8];
                acc[nt] = __builtin_amdgcn_mfma_f32_16x16x32_f16(a, bf, acc[nt], 0, 0, 0);
            }
        }
        if (GROUPED) {
            f16* bw = (f16*)bnc_raw;  // [64][72], wave-private rows
            #pragma unroll
            for (int nt = 0; nt < 4; ++nt)
                #pragma unroll
                for (int r = 0; r < 4; ++r) {
                    float v = acc[nt][r] + bias[ot * 64 + nt * 16 + lo];
                    bw[(w * 16 + hi * 4 + r) * 72 + nt * 16 + lo] = (f16)v;
                }
            int row = w * 16 + (l >> 2);
            #pragma unroll
            for (int j = 0; j < 2; ++j) {
                int col = (l & 3) * 16 + j * 8;
                f16x8 v = *(const f16x8*)&bw[row * 72 + col];
                int o = ot * 64 + col;
                *(f16x8*)&((f16*)out)[((long)(o >> 5) * 131072 + row0 + row) * 32 + (o & 31)] = v;
            }
        } else {
            float* bwf = (float*)bnc_raw;  // [64][68], wave-private rows
            #pragma unroll
            for (int nt = 0; nt < 4; ++nt)
                #pragma unroll
                for (int r = 0; r < 4; ++r) {
                    float v = acc[nt][r] + bias[ot * 64 + nt * 16 + lo];
                    bwf[(w * 16 + hi * 4 + r) * 68 + nt * 16 + lo] = v;
                }
            int row = w * 16 + (l >> 2);
            #pragma unroll
            for (int j = 0; j < 4; ++j) {
                int c4 = ((l & 3) + j * 4) * 4;
                float4v v = *(const float4v*)&bwf[row * 68 + c4];
                *(float4v*)&((float*)out)[(row0 + row) * 192 + ot * 64 + c4] = v;
            }
        }
    }
}

// ---------------------------------------------------------------------------
// Fused depthwise-3x3 conv (packed f16) + xifft residual + MFMA attention.
// Round-15 structure (117 us) with window-swizzled b: halo rows AND the
// producer's T rows are now both chunk-local on this block's XCD L2.
// wd/bd staged in LDS; register prefetch of next s-phase halo; pls overlaid
// on dead tb; LDS 29.4 KB -> 5 blocks/CU.
// ---------------------------------------------------------------------------
__global__ __launch_bounds__(256, 5) void k_attn(
    const f16* __restrict__ T, const f16* __restrict__ xifft,
    const float* __restrict__ dww, const float* __restrict__ dwb,
    f16* __restrict__ obnc)
{
    __shared__ f16 tb[3 * 66 * 32];   // [r][nn+1][ch]; later pls [64][72]
    __shared__ f16 qls[64 * 40];      // q rows; later output bounce
    __shared__ f16 kls[64 * 40];
    __shared__ f16 vtl[32 * 72];      // v transposed
    __shared__ f16 wd[864];           // [s][rj][32]
    __shared__ f16 bd[96];
    const int b = swz_win(blockIdx.x);
    const int h = blockIdx.y, tid = threadIdx.x;
    const int n = tid >> 2, cth = tid & 3;

    for (int idx = tid; idx < 864; idx += 256) {
        int s = idx / 288, rj = (idx % 288) >> 5, d = idx & 31;
        wd[idx] = (f16)dww[(s * 192 + h * 32 + d) * 9 + rj];
    }
    if (tid < 96) {
        int s = tid >> 5, d = tid & 31;
        bd[tid] = (f16)dwb[s * 192 + h * 32 + d];
    }
    if (tid < 24) {    // zero n-pads once (interior writes never touch them)
        int r = tid / 8, pe = (tid >> 2) & 1, cc = tid & 3;
        f16x8 z = {};
        *(f16x8*)&tb[((r * 66) + pe * 65) * 32 + cc * 8] = z;
    }
    f16x8 xf8 = *(const f16x8*)&xifft[(long)b * 12288 + h * 2048 + n * 32 + cth * 8];

    // per-thread staging slots (s-invariant addresses; only group offset moves)
    long  g_off[3];
    int   l_off[3];
    bool  g_val[3];
    #pragma unroll
    for (int it = 0; it < 3; ++it) {
        int idx = tid + it * 256;
        int r = idx >> 8, rem = idx & 255;
        int nn = rem >> 2, cc = rem & 3;
        int bb = b + r - 1;
        g_val[it] = (bb >= 0 && bb < 2048);
        g_off[it] = ((long)bb * 64 + nn) * 32 + cc * 8;
        l_off[it] = (r * 66 + nn + 1) * 32 + cc * 8;
    }
    f16x8 pre[3];
    #pragma unroll
    for (int it = 0; it < 3; ++it) {
        f16x8 v = {};
        if (g_val[it]) v = *(const f16x8*)&T[(long)h * 4194304 + g_off[it]];  // s=0
        pre[it] = v;
    }
    __syncthreads();   // wd/bd/pads staged

    for (int s = 0; s < 3; ++s) {
        #pragma unroll
        for (int it = 0; it < 3; ++it)
            *(f16x8*)&tb[l_off[it]] = pre[it];
        if (s < 2) {   // issue next phase's loads; latency hides under conv
            #pragma unroll
            for (int it = 0; it < 3; ++it) {
                f16x8 v = {};
                if (g_val[it])
                    v = *(const f16x8*)&T[(long)((s + 1) * 6 + h) * 4194304 + g_off[it]];
                pre[it] = v;
            }
        }
        __syncthreads();   // tb visible
        f16x8 acc = *(const f16x8*)&bd[s * 32 + cth * 8];
        #pragma unroll
        for (int rj = 0; rj < 9; ++rj) {
            f16x8 tv = *(const f16x8*)&tb[((rj / 3) * 66 + n + rj % 3) * 32 + cth * 8];
            f16x8 wv = *(const f16x8*)&wd[(s * 9 + rj) * 32 + cth * 8];
            acc += wv * tv;
        }
        acc += xf8;
        if (s == 0) {
            acc *= (f16)SCALE_Q;
            *(f16x8*)&qls[n * 40 + cth * 8] = acc;
        } else if (s == 1) {
            *(f16x8*)&kls[n * 40 + cth * 8] = acc;
        } else {
            // stagger dd by cth -> conflict-free vtl scalar writes
            #pragma unroll
            for (int dd = 0; dd < 8; ++dd) {
                int dd2 = (dd + cth * 2) & 7;
                vtl[(cth * 8 + dd2) * 72 + n] = acc[dd2];
            }
        }
        __syncthreads();   // conv reads of tb done (also final q/k/v fence at s=2)
    }

    f16* pls = tb;     // tb dead -> reuse as pls [64][72]

    // QK^T
    const int w = tid >> 6, l = tid & 63, lo = l & 15, hi = l >> 4;
    f16x8 qfrag = *(const f16x8*)&qls[(w * 16 + lo) * 40 + hi * 8];
    float4v accq[4];
    #pragma unroll
    for (int mt = 0; mt < 4; ++mt) {
        f16x8 kfrag = *(const f16x8*)&kls[(mt * 16 + lo) * 40 + hi * 8];
        accq[mt] = __builtin_amdgcn_mfma_f32_16x16x32_f16(
            qfrag, kfrag, (float4v){0.f, 0.f, 0.f, 0.f}, 0, 0, 0);
    }

    // bias + softmax in C-layout registers
    const f16* bg = g_biasg + h * 4096;
    float pv[4][4];
    #pragma unroll
    for (int mt = 0; mt < 4; ++mt)
        #pragma unroll
        for (int r = 0; r < 4; ++r)
            pv[mt][r] = accq[mt][r] + (float)bg[(w * 16 + hi * 4 + r) * 64 + mt * 16 + lo];
    float inv[4];
    #pragma unroll
    for (int r = 0; r < 4; ++r) {
        float mx = fmaxf(fmaxf(pv[0][r], pv[1][r]), fmaxf(pv[2][r], pv[3][r]));
        mx = fmaxf(mx, __shfl_xor(mx, 1));
        mx = fmaxf(mx, __shfl_xor(mx, 2));
        mx = fmaxf(mx, __shfl_xor(mx, 4));
        mx = fmaxf(mx, __shfl_xor(mx, 8));
        float sum = 0.f;
        #pragma unroll
        for (int mt = 0; mt < 4; ++mt) { pv[mt][r] = __expf(pv[mt][r] - mx); sum += pv[mt][r]; }
        sum += __shfl_xor(sum, 1);
        sum += __shfl_xor(sum, 2);
        sum += __shfl_xor(sum, 4);
        sum += __shfl_xor(sum, 8);
        inv[r] = 1.0f / sum;
    }
    #pragma unroll
    for (int mt = 0; mt < 4; ++mt)
        #pragma unroll
        for (int r = 0; r < 4; ++r)
            pls[(w * 16 + hi * 4 + r) * 72 + mt * 16 + lo] = (f16)(pv[mt][r] * inv[r]);
    // pls rows are written AND read only by their own wave -> no barrier

    // PV
    float4v acco[2] = {(float4v){0.f,0.f,0.f,0.f}, (float4v){0.f,0.f,0.f,0.f}};
    #pragma unroll
    for (int kc = 0; kc < 2; ++kc) {
        f16x8 pfrag = *(const f16x8*)&pls[(w * 16 + lo) * 72 + kc * 32 + hi * 8];
        #pragma unroll
        for (int dt = 0; dt < 2; ++dt) {
            f16x8 vfrag = *(const f16x8*)&vtl[(dt * 16 + lo) * 72 + kc * 32 + hi * 8];
            acco[dt] = __builtin_amdgcn_mfma_f32_16x16x32_f16(pfrag, vfrag, acco[dt], 0, 0, 0);
        }
    }
    // bounce output through qls (dead, wave-own rows) -> coalesced f16x8 stores
    #pragma unroll
    for (int dt = 0; dt < 2; ++dt)
        #pragma unroll
        for (int r = 0; r < 4; ++r)
            qls[(w * 16 + hi * 4 + r) * 40 + dt * 16 + lo] = (f16)acco[dt][r];
    {
        int row = w * 16 + (l >> 2);
        f16x8 ov = *(const f16x8*)&qls[row * 40 + (l & 3) * 8];
        *(f16x8*)&obnc[((long)b * 64 + row) * 192 + h * 32 + (l & 3) * 8] = ov;
    }
}

// ---------------------------------------------------------------------------
// Launcher. Workspace (f16 elems), 251,953,152 bytes total:
//   T    [0, 75497472)           : qkv conv output, grouped [18][131072][32]
//   q1f  = T[25165824, +36864)   : q1 fragment-order (alias; dead before qkv)
//   q2f  = T[25202688, +36864)   : q2 fragment-order (alias; dead before qkv)
//   XI   [75497472, 100663296)   : xifft
//   O    [100663296, 125829120)  : obnc [bn][192]
//   WB   [125829120, +147456)    : qkvf | projf (fragment order, persistent)
// ---------------------------------------------------------------------------
extern "C" void kernel_launch(void* const* d_in, const int* in_sizes, int n_in,
                              void* d_out, int out_size, void* d_ws, size_t ws_size,
                              hipStream_t stream)
{
    const float* x      = (const float*)d_in[0];
    const float* qkvw   = (const float*)d_in[1];
    const float* qkvb   = (const float*)d_in[2];
    const float* dww    = (const float*)d_in[3];
    const float* dwb    = (const float*)d_in[4];
    const float* q1w    = (const float*)d_in[5];
    const float* q2w    = (const float*)d_in[6];
    const float* rpb    = (const float*)d_in[7];
    const float* projw  = (const float*)d_in[8];
    const float* projb  = (const float*)d_in[9];
    const int*   relidx = (const int*)d_in[10];

    f16* T    = (f16*)d_ws;
    f16* q1f  = T + 25165824L;              // alias: dead before qkv-gemm writes T
    f16* q2f  = T + 25202688L;
    f16* XI   = T + 75497472L;
    f16* O    = XI + 25165824L;
    f16* WB   = O + 25165824L;
    f16* qkvf  = WB;
    f16* projf = WB + 110592;

    k_prep<<<960, 256, 0, stream>>>(qkvw, q1w, q2w, projw, rpb, relidx,
                                    qkvf, projf, q1f, q2f);

    // fused FFT branch (stages+transposes x internally) -> xifft
    k_fft<<<2048, 512, 0, stream>>>(x, q1f, q2f, XI);

    // t = x @ qkv_w^T + qkv_b  (grouped [18][bn][32], f16)
    gemm_frag<9, true><<<2048, 256, 0, stream>>>(x, qkvf, qkvb, T);

    // fused depthwise conv + residual + MFMA attention -> obnc f16
    k_attn<<<dim3(2048, 6), 256, 0, stream>>>(T, XI, dww, dwb, O);

    // final projection -> d_out f32
    gemm_frag<3, false><<<2048, 256, 0, stream>>>(O, projf, projb, (float*)d_out);
}

// Round 21
// 311.445 us; speedup vs baseline: 1.0203x; 1.0203x over previous
//
#include <hip/hip_runtime.h>
#include <math.h>

// B=2048 windows, N=64 tokens, C=192 channels, 6 heads x 32 dim, 3C=576
#define SCALE_Q 0.17677669529663687f

typedef _Float16 f16;
typedef _Float16 f16x4 __attribute__((ext_vector_type(4)));
typedef _Float16 f16x8 __attribute__((ext_vector_type(8)));
typedef float float4v __attribute__((ext_vector_type(4)));

// Precomputed relative-position bias tile [6][64][64] (f16), L2-hot at use.
__device__ f16 g_biasg[6 * 64 * 64];

// cos(k*pi/4), k in [0,8) — branchless
__device__ __forceinline__ float cos8(int k) {
    float m = (k & 1) ? 0.70710678118654752f : ((k & 2) ? 0.f : 1.f);
    return (k >= 3 && k <= 5) ? -m : m;
}

// Fast GELU: A&S 7.1.26 erf approx, |err| <= 1.5e-7.
__device__ __forceinline__ float gelu_f(float v) {
    float az = fabsf(v) * 0.70710678118654752f;
    float t = 1.0f / fmaf(az, 0.3275911f, 1.0f);
    float p = t * fmaf(t, fmaf(t, fmaf(t, fmaf(t, 1.061405429f, -1.453152027f),
                                       1.421413741f), -0.284496736f), 0.254829592f);
    float erfv = 1.0f - p * __expf(-az * az);
    erfv = copysignf(erfv, v);
    return 0.5f * v * (1.0f + erfv);
}

// ---------------------------------------------------------------------------
// Prep: all weights to f16 MFMA-fragment order (512 elems/fragment):
//   Wf[(o16*6+kc)*512 + lane*8 + j] = W[o16*16+(lane&15)][kc*32+(lane>>4)*8+j]
// qkvf (576x192) | projf (192x192) | q1f | q2f (192x192) + bias tile.
// ---------------------------------------------------------------------------
__global__ __launch_bounds__(256) void k_prep(
    const float* __restrict__ qkvw, const float* __restrict__ q1w,
    const float* __restrict__ q2w, const float* __restrict__ projw,
    const float* __restrict__ rpb, const int* __restrict__ relidx,
    f16* __restrict__ qkvf, f16* __restrict__ projf,
    f16* __restrict__ q1f, f16* __restrict__ q2f)
{
    int idx = blockIdx.x * 256 + threadIdx.x;
    if (idx < 221184) {
        int i = idx;
        const float* src;
        f16* dst;
        if (i < 110592)      { src = qkvw;  dst = qkvf; }
        else if (i < 147456) { i -= 110592; src = projw; dst = projf; }
        else if (i < 184320) { i -= 147456; src = q1w;   dst = q1f; }
        else                 { i -= 184320; src = q2w;   dst = q2f; }
        int frag = i >> 9, rem = i & 511;
        int lane = rem >> 3, j = rem & 7;
        int o16 = frag / 6, kc = frag - o16 * 6;
        int row = o16 * 16 + (lane & 15);
        int col = kc * 32 + (lane >> 4) * 8 + j;
        dst[i] = (f16)src[row * 192 + col];
    } else if (idx < 245760) {
        int i = idx - 221184;
        int h = i >> 12, nm = i & 4095;
        g_biasg[h * 4096 + nm] = (f16)rpb[relidx[nm] * 6 + h];
    }
}

// ---------------------------------------------------------------------------
// Fully fused FFT branch, one block (512 thr, 8 waves) per window.
// Stages x f32: coalesced loads -> Y (row-major, stride 198) -> vectorized
// transpose pass (8 scalar LDS reads -> one f16x8 write) -> XT channel-major.
// ph1/ph4: rw=w&3, ch=w>>2; DFT matrix per-lane (cos8).
// ph2/ph3: h2=w&1, q4=w>>1; weights from q1f/q2f fragment-order (L2-hot).
// LDS: XT[192][72] (x^T, later y2 [64][216]) + Y[64][200].
// ---------------------------------------------------------------------------
__global__ __launch_bounds__(512, 4) void k_fft(
    const float* __restrict__ x, const f16* __restrict__ q1f,
    const f16* __restrict__ q2f, f16* __restrict__ xifft)
{
    __shared__ f16 XT[192 * 72];
    __shared__ f16 Y[64 * 200];
    const int b = blockIdx.x, tid = threadIdx.x;
    const long gbase = (long)b * 12288;
    const int w = tid >> 6, l = tid & 63, lo = l & 15, hi = l >> 4;
    const int rw = w & 3, ch = w >> 2;
    const int h2 = w & 1, q4 = w >> 1;

    // stage a: x f32 coalesced -> Y row-major f16 (stride 198)
    #pragma unroll
    for (int it = 0; it < 6; ++it) {
        int idx = tid + it * 512;            // 3072 float4s
        int r = idx / 48, c4 = idx % 48;
        float4v v = *(const float4v*)&x[gbase + r * 192 + c4 * 4];
        f16x4 hv = {(f16)v.x, (f16)v.y, (f16)v.z, (f16)v.w};
        *(f16x4*)&Y[r * 198 + c4 * 4] = hv;
    }
    __syncthreads();
    // stage b: transpose Y -> XT[c][hw], vector writes
    #pragma unroll
    for (int it = 0; it < 3; ++it) {
        int idx = tid + it * 512;            // 1536 f16x8 tasks
        int c = idx >> 3, g8 = idx & 7;
        f16x8 o;
        #pragma unroll
        for (int j = 0; j < 8; ++j) o[j] = Y[(g8 * 8 + j) * 198 + c];
        *(f16x8*)&XT[c * 72 + g8 * 8] = o;
    }
    __syncthreads();

    // ph1: y1[uv][c] = sum_hw L[uv][hw] x^T[c][hw]
    {
        f16x8 afr[2];
        int u = (rw * 16 + lo) >> 3, v = (rw * 16 + lo) & 7;
        #pragma unroll
        for (int kc = 0; kc < 2; ++kc) {
            int cg = kc * 4 + hi;
            #pragma unroll
            for (int e = 0; e < 8; ++e)
                afr[kc][e] = (f16)cos8((u * cg + v * e) & 7);
        }
        float4v acc[6];
        #pragma unroll
        for (int nt = 0; nt < 6; ++nt) acc[nt] = (float4v){0.f,0.f,0.f,0.f};
        #pragma unroll
        for (int kc = 0; kc < 2; ++kc)
            #pragma unroll
            for (int nt = 0; nt < 6; ++nt) {
                f16x8 bf = *(const f16x8*)&XT[(ch * 96 + nt * 16 + lo) * 72 + kc * 32 + hi * 8];
                acc[nt] = __builtin_amdgcn_mfma_f32_16x16x32_f16(afr[kc], bf, acc[nt], 0, 0, 0);
            }
        __syncthreads();   // staging reads of Y done before y1 overwrite
        #pragma unroll
        for (int nt = 0; nt < 6; ++nt)
            #pragma unroll
            for (int r = 0; r < 4; ++r)
                Y[(rw * 16 + hi * 4 + r) * 200 + ch * 96 + nt * 16 + lo] = (f16)acc[nt][r];
    }
    __syncthreads();   // y1 visible; XT(x^T) reads done

    // ph2: y2[uv][o] = gelu(sum_c y1[uv][c] q1[o][c]) -> XT region, stride 216
    {
        float4v acc[2][3];
        #pragma unroll
        for (int mt = 0; mt < 2; ++mt)
            #pragma unroll
            for (int nj = 0; nj < 3; ++nj) acc[mt][nj] = (float4v){0.f,0.f,0.f,0.f};
        for (int kc = 0; kc < 6; ++kc) {
            f16x8 a[2];
            #pragma unroll
            for (int mt = 0; mt < 2; ++mt)
                a[mt] = *(const f16x8*)&Y[(h2 * 32 + mt * 16 + lo) * 200 + kc * 32 + hi * 8];
            #pragma unroll
            for (int nj = 0; nj < 3; ++nj) {
                f16x8 bf = *(const f16x8*)&q1f[((q4 * 3 + nj) * 6 + kc) * 512 + l * 8];
                #pragma unroll
                for (int mt = 0; mt < 2; ++mt)
                    acc[mt][nj] = __builtin_amdgcn_mfma_f32_16x16x32_f16(a[mt], bf, acc[mt][nj], 0, 0, 0);
            }
        }
        f16* y2 = XT;
        #pragma unroll
        for (int mt = 0; mt < 2; ++mt)
            #pragma unroll
            for (int nj = 0; nj < 3; ++nj)
                #pragma unroll
                for (int r = 0; r < 4; ++r)
                    y2[(h2 * 32 + mt * 16 + hi * 4 + r) * 216 + (q4 * 3 + nj) * 16 + lo] =
                        (f16)gelu_f(acc[mt][nj][r]);
    }
    __syncthreads();   // y2 visible; Y(y1) reads done

    // ph3: y3T[o][uv] = sum_c q2[o][c] y2[uv][c] -> Y region, swizzled cols
    {
        const f16* y2 = XT;
        float4v acc[3][2];
        #pragma unroll
        for (int jo = 0; jo < 3; ++jo)
            #pragma unroll
            for (int ju = 0; ju < 2; ++ju) acc[jo][ju] = (float4v){0.f,0.f,0.f,0.f};
        for (int kc = 0; kc < 6; ++kc) {
            f16x8 bf2[2];
            #pragma unroll
            for (int ju = 0; ju < 2; ++ju)
                bf2[ju] = *(const f16x8*)&y2[((h2 * 2 + ju) * 16 + lo) * 216 + kc * 32 + hi * 8];
            #pragma unroll
            for (int jo = 0; jo < 3; ++jo) {
                f16x8 a = *(const f16x8*)&q2f[((q4 * 3 + jo) * 6 + kc) * 512 + l * 8];
                #pragma unroll
                for (int ju = 0; ju < 2; ++ju)
                    acc[jo][ju] = __builtin_amdgcn_mfma_f32_16x16x32_f16(a, bf2[ju], acc[jo][ju], 0, 0, 0);
            }
        }
        __syncthreads();   // y2 reads done before overwriting Y
        #pragma unroll
        for (int jo = 0; jo < 3; ++jo)
            #pragma unroll
            for (int ju = 0; ju < 2; ++ju)
                #pragma unroll
                for (int r = 0; r < 4; ++r) {
                    int row = (q4 * 3 + jo) * 16 + hi * 4 + r;
                    int col = (h2 * 2 + ju) * 16 + lo;
                    Y[row * 64 + (col ^ ((row & 7) << 3))] = (f16)acc[jo][ju][r];
                }
    }
    __syncthreads();   // y3T visible

    // ph4: xifft[o][hw] = (1/64) sum_uv y3T[o][uv] L[hw][uv]
    {
        f16x8 bfr[2][2];
        #pragma unroll
        for (int t = 0; t < 2; ++t) {
            int hw = (ch * 2 + t) * 16 + lo;
            int hu = hw >> 3, hv = hw & 7;
            #pragma unroll
            for (int kc = 0; kc < 2; ++kc) {
                int cg = kc * 4 + hi;
                #pragma unroll
                for (int e = 0; e < 8; ++e)
                    bfr[t][kc][e] = (f16)cos8((hu * cg + hv * e) & 7);
            }
        }
        float4v acc[6];
        #pragma unroll
        for (int jt = 0; jt < 6; ++jt) acc[jt] = (float4v){0.f,0.f,0.f,0.f};
        #pragma unroll
        for (int kc = 0; kc < 2; ++kc)
            #pragma unroll
            for (int j = 0; j < 3; ++j) {
                int row = (rw * 3 + j) * 16 + lo;
                f16x8 a = *(const f16x8*)&Y[row * 64 + ((kc * 32 + hi * 8) ^ ((row & 7) << 3))];
                #pragma unroll
                for (int t = 0; t < 2; ++t)
                    acc[j * 2 + t] = __builtin_amdgcn_mfma_f32_16x16x32_f16(a, bfr[t][kc], acc[j * 2 + t], 0, 0, 0);
            }
        #pragma unroll
        for (int j = 0; j < 3; ++j)
            #pragma unroll
            for (int t = 0; t < 2; ++t)
                #pragma unroll
                for (int r = 0; r < 4; ++r)
                    xifft[gbase + ((rw * 3 + j) * 16 + hi * 4 + r) * 64 + (ch * 2 + t) * 16 + lo] =
                        (f16)(acc[j * 2 + t][r] * 0.015625f);
    }
}

// ---------------------------------------------------------------------------
// fp16 MFMA GEMM, K=192, weights in fragment order (no Ws staging, no loop
// barriers; epilogue bounce rows are wave-private -> barrier-free).
// GROUPED=true : A f32 (x), out grouped [(o/32)][row][o%32] f16 (qkv).
// GROUPED=false: A f16, out row-major [M][192] f32 (proj).
// ---------------------------------------------------------------------------
template<int NT, bool GROUPED>
__global__ __launch_bounds__(256) void gemm_frag(
    const void* __restrict__ Ain, const f16* __restrict__ Wf,
    const float* __restrict__ bias, void* __restrict__ out)
{
    __shared__ f16 As[64 * 200];
    __shared__ char bnc_raw[GROUPED ? 64 * 72 * 2 : 64 * 68 * 4];
    const int tid = threadIdx.x;
    const long row0 = (long)blockIdx.x * 64;
    const int w = tid >> 6, l = tid & 63, lo = l & 15, hi = l >> 4;

    if (GROUPED) {
        const float* A = (const float*)Ain;
        for (int idx = tid; idx < 3072; idx += 256) {
            int r = idx / 48, c4 = idx % 48;
            float4v v = *(const float4v*)&A[(row0 + r) * 192 + c4 * 4];
            f16x4 hv = {(f16)v.x, (f16)v.y, (f16)v.z, (f16)v.w};
            *(f16x4*)&As[r * 200 + c4 * 4] = hv;
        }
    } else {
        const f16* A = (const f16*)Ain;
        for (int idx = tid; idx < 1536; idx += 256) {
            int r = idx / 24, c8 = idx % 24;
            *(f16x8*)&As[r * 200 + c8 * 8] =
                *(const f16x8*)&A[(row0 + r) * 192 + c8 * 8];
        }
    }
    __syncthreads();

    for (int ot = 0; ot < NT; ++ot) {
        float4v acc[4];
        #pragma unroll
        for (int nt = 0; nt < 4; ++nt) acc[nt] = (float4v){0.f,0.f,0.f,0.f};
        #pragma unroll
        for (int kc = 0; kc < 6; ++kc) {
            f16x8 a = *(const f16x8*)&As[(w * 16 + lo) * 200 + kc * 32 + hi * 8];
            #pragma unroll
            for (int nt = 0; nt < 4; ++nt) {
                f16x8 bf = *(const f16x8*)&Wf[(long)(((ot * 4 + nt) * 6 + kc)) * 512 + l * 8];
                acc[nt] = __builtin_amdgcn_mfma_f32_16x16x32_f16(a, bf, acc[nt], 0, 0, 0);
            }
        }
        if (GROUPED) {
            f16* bw = (f16*)bnc_raw;  // [64][72], wave-private rows
            #pragma unroll
            for (int nt = 0; nt < 4; ++nt)
                #pragma unroll
                for (int r = 0; r < 4; ++r) {
                    float v = acc[nt][r] + bias[ot * 64 + nt * 16 + lo];
                    bw[(w * 16 + hi * 4 + r) * 72 + nt * 16 + lo] = (f16)v;
                }
            int row = w * 16 + (l >> 2);
            #pragma unroll
            for (int j = 0; j < 2; ++j) {
                int col = (l & 3) * 16 + j * 8;
                f16x8 v = *(const f16x8*)&bw[row * 72 + col];
                int o = ot * 64 + col;
                *(f16x8*)&((f16*)out)[((long)(o >> 5) * 131072 + row0 + row) * 32 + (o & 31)] = v;
            }
        } else {
            float* bwf = (float*)bnc_raw;  // [64][68], wave-private rows
            #pragma unroll
            for (int nt = 0; nt < 4; ++nt)
                #pragma unroll
                for (int r = 0; r < 4; ++r) {
                    float v = acc[nt][r] + bias[ot * 64 + nt * 16 + lo];
                    bwf[(w * 16 + hi * 4 + r) * 68 + nt * 16 + lo] = v;
                }
            int row = w * 16 + (l >> 2);
            #pragma unroll
            for (int j = 0; j < 4; ++j) {
                int c4 = ((l & 3) + j * 4) * 4;
                float4v v = *(const float4v*)&bwf[row * 68 + c4];
                *(float4v*)&((float*)out)[(row0 + row) * 192 + ot * 64 + c4] = v;
            }
        }
    }
}

// ---------------------------------------------------------------------------
// Fused depthwise-3x3 conv (packed f16) + xifft residual + MFMA attention.
// Best-measured configuration (117 us, VGPR 44, no scratch): wd/bd staged in
// LDS; register prefetch of next s-phase halo; pls overlaid on dead tb;
// LDS 29.4 KB -> 5 blocks/CU.
// ---------------------------------------------------------------------------
__global__ __launch_bounds__(256, 5) void k_attn(
    const f16* __restrict__ T, const f16* __restrict__ xifft,
    const float* __restrict__ dww, const float* __restrict__ dwb,
    f16* __restrict__ obnc)
{
    __shared__ f16 tb[3 * 66 * 32];   // [r][nn+1][ch]; later pls [64][72]
    __shared__ f16 qls[64 * 40];      // q rows; later output bounce
    __shared__ f16 kls[64 * 40];
    __shared__ f16 vtl[32 * 72];      // v transposed
    __shared__ f16 wd[864];           // [s][rj][32]
    __shared__ f16 bd[96];
    const int b = blockIdx.x;
    const int h = blockIdx.y, tid = threadIdx.x;
    const int n = tid >> 2, cth = tid & 3;

    for (int idx = tid; idx < 864; idx += 256) {
        int s = idx / 288, rj = (idx % 288) >> 5, d = idx & 31;
        wd[idx] = (f16)dww[(s * 192 + h * 32 + d) * 9 + rj];
    }
    if (tid < 96) {
        int s = tid >> 5, d = tid & 31;
        bd[tid] = (f16)dwb[s * 192 + h * 32 + d];
    }
    if (tid < 24) {    // zero n-pads once (interior writes never touch them)
        int r = tid / 8, pe = (tid >> 2) & 1, cc = tid & 3;
        f16x8 z = {};
        *(f16x8*)&tb[((r * 66) + pe * 65) * 32 + cc * 8] = z;
    }
    f16x8 xf8 = *(const f16x8*)&xifft[(long)b * 12288 + h * 2048 + n * 32 + cth * 8];

    // per-thread staging slots (s-invariant addresses; only group offset moves)
    long  g_off[3];
    int   l_off[3];
    bool  g_val[3];
    #pragma unroll
    for (int it = 0; it < 3; ++it) {
        int idx = tid + it * 256;
        int r = idx >> 8, rem = idx & 255;
        int nn = rem >> 2, cc = rem & 3;
        int bb = b + r - 1;
        g_val[it] = (bb >= 0 && bb < 2048);
        g_off[it] = ((long)bb * 64 + nn) * 32 + cc * 8;
        l_off[it] = (r * 66 + nn + 1) * 32 + cc * 8;
    }
    f16x8 pre[3];
    #pragma unroll
    for (int it = 0; it < 3; ++it) {
        f16x8 v = {};
        if (g_val[it]) v = *(const f16x8*)&T[(long)h * 4194304 + g_off[it]];  // s=0
        pre[it] = v;
    }
    __syncthreads();   // wd/bd/pads staged

    for (int s = 0; s < 3; ++s) {
        #pragma unroll
        for (int it = 0; it < 3; ++it)
            *(f16x8*)&tb[l_off[it]] = pre[it];
        if (s < 2) {   // issue next phase's loads; latency hides under conv
            #pragma unroll
            for (int it = 0; it < 3; ++it) {
                f16x8 v = {};
                if (g_val[it])
                    v = *(const f16x8*)&T[(long)((s + 1) * 6 + h) * 4194304 + g_off[it]];
                pre[it] = v;
            }
        }
        __syncthreads();   // tb visible
        f16x8 acc = *(const f16x8*)&bd[s * 32 + cth * 8];
        #pragma unroll
        for (int rj = 0; rj < 9; ++rj) {
            f16x8 tv = *(const f16x8*)&tb[((rj / 3) * 66 + n + rj % 3) * 32 + cth * 8];
            f16x8 wv = *(const f16x8*)&wd[(s * 9 + rj) * 32 + cth * 8];
            acc += wv * tv;
        }
        acc += xf8;
        if (s == 0) {
            acc *= (f16)SCALE_Q;
            *(f16x8*)&qls[n * 40 + cth * 8] = acc;
        } else if (s == 1) {
            *(f16x8*)&kls[n * 40 + cth * 8] = acc;
        } else {
            // stagger dd by cth -> conflict-free vtl scalar writes
            #pragma unroll
            for (int dd = 0; dd < 8; ++dd) {
                int dd2 = (dd + cth * 2) & 7;
                vtl[(cth * 8 + dd2) * 72 + n] = acc[dd2];
            }
        }
        __syncthreads();   // conv reads of tb done (also final q/k/v fence at s=2)
    }

    f16* pls = tb;     // tb dead -> reuse as pls [64][72]

    // QK^T
    const int w = tid >> 6, l = tid & 63, lo = l & 15, hi = l >> 4;
    f16x8 qfrag = *(const f16x8*)&qls[(w * 16 + lo) * 40 + hi * 8];
    float4v accq[4];
    #pragma unroll
    for (int mt = 0; mt < 4; ++mt) {
        f16x8 kfrag = *(const f16x8*)&kls[(mt * 16 + lo) * 40 + hi * 8];
        accq[mt] = __builtin_amdgcn_mfma_f32_16x16x32_f16(
            qfrag, kfrag, (float4v){0.f, 0.f, 0.f, 0.f}, 0, 0, 0);
    }

    // bias + softmax in C-layout registers
    const f16* bg = g_biasg + h * 4096;
    float pv[4][4];
    #pragma unroll
    for (int mt = 0; mt < 4; ++mt)
        #pragma unroll
        for (int r = 0; r < 4; ++r)
            pv[mt][r] = accq[mt][r] + (float)bg[(w * 16 + hi * 4 + r) * 64 + mt * 16 + lo];
    float inv[4];
    #pragma unroll
    for (int r = 0; r < 4; ++r) {
        float mx = fmaxf(fmaxf(pv[0][r], pv[1][r]), fmaxf(pv[2][r], pv[3][r]));
        mx = fmaxf(mx, __shfl_xor(mx, 1));
        mx = fmaxf(mx, __shfl_xor(mx, 2));
        mx = fmaxf(mx, __shfl_xor(mx, 4));
        mx = fmaxf(mx, __shfl_xor(mx, 8));
        float sum = 0.f;
        #pragma unroll
        for (int mt = 0; mt < 4; ++mt) { pv[mt][r] = __expf(pv[mt][r] - mx); sum += pv[mt][r]; }
        sum += __shfl_xor(sum, 1);
        sum += __shfl_xor(sum, 2);
        sum += __shfl_xor(sum, 4);
        sum += __shfl_xor(sum, 8);
        inv[r] = 1.0f / sum;
    }
    #pragma unroll
    for (int mt = 0; mt < 4; ++mt)
        #pragma unroll
        for (int r = 0; r < 4; ++r)
            pls[(w * 16 + hi * 4 + r) * 72 + mt * 16 + lo] = (f16)(pv[mt][r] * inv[r]);
    // pls rows are written AND read only by their own wave -> no barrier

    // PV
    float4v acco[2] = {(float4v){0.f,0.f,0.f,0.f}, (float4v){0.f,0.f,0.f,0.f}};
    #pragma unroll
    for (int kc = 0; kc < 2; ++kc) {
        f16x8 pfrag = *(const f16x8*)&pls[(w * 16 + lo) * 72 + kc * 32 + hi * 8];
        #pragma unroll
        for (int dt = 0; dt < 2; ++dt) {
            f16x8 vfrag = *(const f16x8*)&vtl[(dt * 16 + lo) * 72 + kc * 32 + hi * 8];
            acco[dt] = __builtin_amdgcn_mfma_f32_16x16x32_f16(pfrag, vfrag, acco[dt], 0, 0, 0);
        }
    }
    // bounce output through qls (dead, wave-own rows) -> coalesced f16x8 stores
    #pragma unroll
    for (int dt = 0; dt < 2; ++dt)
        #pragma unroll
        for (int r = 0; r < 4; ++r)
            qls[(w * 16 + hi * 4 + r) * 40 + dt * 16 + lo] = (f16)acco[dt][r];
    {
        int row = w * 16 + (l >> 2);
        f16x8 ov = *(const f16x8*)&qls[row * 40 + (l & 3) * 8];
        *(f16x8*)&obnc[((long)b * 64 + row) * 192 + h * 32 + (l & 3) * 8] = ov;
    }
}

// ---------------------------------------------------------------------------
// Launcher. Workspace (f16 elems), 251,953,152 bytes total:
//   T    [0, 75497472)           : qkv conv output, grouped [18][131072][32]
//   q1f  = T[25165824, +36864)   : q1 fragment-order (alias; dead before qkv)
//   q2f  = T[25202688, +36864)   : q2 fragment-order (alias; dead before qkv)
//   XI   [75497472, 100663296)   : xifft
//   O    [100663296, 125829120)  : obnc [bn][192]
//   WB   [125829120, +147456)    : qkvf | projf (fragment order, persistent)
// ---------------------------------------------------------------------------
extern "C" void kernel_launch(void* const* d_in, const int* in_sizes, int n_in,
                              void* d_out, int out_size, void* d_ws, size_t ws_size,
                              hipStream_t stream)
{
    const float* x      = (const float*)d_in[0];
    const float* qkvw   = (const float*)d_in[1];
    const float* qkvb   = (const float*)d_in[2];
    const float* dww    = (const float*)d_in[3];
    const float* dwb    = (const float*)d_in[4];
    const float* q1w    = (const float*)d_in[5];
    const float* q2w    = (const float*)d_in[6];
    const float* rpb    = (const float*)d_in[7];
    const float* projw  = (const float*)d_in[8];
    const float* projb  = (const float*)d_in[9];
    const int*   relidx = (const int*)d_in[10];

    f16* T    = (f16*)d_ws;
    f16* q1f  = T + 25165824L;              // alias: dead before qkv-gemm writes T
    f16* q2f  = T + 25202688L;
    f16* XI   = T + 75497472L;
    f16* O    = XI + 25165824L;
    f16* WB   = O + 25165824L;
    f16* qkvf  = WB;
    f16* projf = WB + 110592;

    k_prep<<<960, 256, 0, stream>>>(qkvw, q1w, q2w, projw, rpb, relidx,
                                    qkvf, projf, q1f, q2f);

    // fused FFT branch (stages+transposes x internally) -> xifft
    k_fft<<<2048, 512, 0, stream>>>(x, q1f, q2f, XI);

    // t = x @ qkv_w^T + qkv_b  (grouped [18][bn][32], f16)
    gemm_frag<9, true><<<2048, 256, 0, stream>>>(x, qkvf, qkvb, T);

    // fused depthwise conv + residual + MFMA attention -> obnc f16
    k_attn<<<dim3(2048, 6), 256, 0, stream>>>(T, XI, dww, dwb, O);

    // final projection -> d_out f32
    gemm_frag<3, false><<<2048, 256, 0, stream>>>(O, projf, projb, (float*)d_out);
}